// Round 1
// baseline (188.555 us; speedup 1.0000x reference)
//
#include <hip/hip_runtime.h>
#include <hip/hip_bf16.h>

#define N 8192
#define D 200
#define KP 224      // K padded to 7 * 32
#define NSTEP 7

typedef __bf16 bf16x8 __attribute__((ext_vector_type(8)));
typedef float f32x4 __attribute__((ext_vector_type(4)));

// ---------------- prep: cast to bf16 (padded), row norms, labels, zero acc ----
__global__ __launch_bounds__(256) void prep_kernel(
    const float* __restrict__ x, const int* __restrict__ labels,
    __hip_bfloat16* __restrict__ xb, float* __restrict__ sq,
    int* __restrict__ lab, float* __restrict__ accrow) {
  int row = blockIdx.x * 4 + (threadIdx.x >> 6);   // one wave per row
  int lane = threadIdx.x & 63;
  const float* xr = x + (size_t)row * D;
  __hip_bfloat16* xbr = xb + (size_t)row * KP;
  float s = 0.f;
#pragma unroll
  for (int c = 0; c < 4; ++c) {
    int k = lane + c * 64;                          // covers 0..255
    float f = (k < D) ? xr[k] : 0.f;
    __hip_bfloat16 h = __float2bfloat16(f);
    float fb = __bfloat162float(h);
    if (k < KP) xbr[k] = h;
    s += fb * fb;                                   // norm of the bf16-rounded row
  }
#pragma unroll
  for (int m = 32; m; m >>= 1) s += __shfl_xor(s, m);
  if (lane == 0) {
    sq[row] = s;
    lab[row] = labels[row];
    accrow[row] = 0.f;                              // ws is poisoned each call
  }
}

// ---------------- 128x128 MFMA tile + fused distance/sign/row-sum epilogue ----
__global__ __launch_bounds__(256) void gram_kernel(
    const __hip_bfloat16* __restrict__ xb, const float* __restrict__ sq,
    const int* __restrict__ lab, float* __restrict__ accrow) {
  // rows padded 32 -> 40 elems (80 B = 20 dwords): bank stride cycles all 32 banks
  __shared__ __align__(16) __hip_bfloat16 As[128][40];
  __shared__ __align__(16) __hip_bfloat16 Bs[128][40];

  const int bi = blockIdx.y, bj = blockIdx.x;
  const int t = threadIdx.x;
  const int wid = t >> 6, lane = t & 63;
  const int col = lane & 15, quad = lane >> 4;
  const int waveM = (wid >> 1) * 64, waveN = (wid & 1) * 64;

  const uint4* xv = (const uint4*)xb;               // 8 bf16 per uint4; row stride 28

  f32x4 acc[4][4] = {};

  const int arow = t >> 2, ag = t & 3;              // staging: (row, 8-elem group)
  for (int step = 0; step < NSTEP; ++step) {
#pragma unroll
    for (int h = 0; h < 2; ++h) {
      int row = arow + h * 64;
      uint4 va = xv[(size_t)(bi * 128 + row) * 28 + step * 4 + ag];
      uint4 vb = xv[(size_t)(bj * 128 + row) * 28 + step * 4 + ag];
      *(uint4*)&As[row][ag * 8] = va;
      *(uint4*)&Bs[row][ag * 8] = vb;
    }
    __syncthreads();
    bf16x8 a[4], b[4];
#pragma unroll
    for (int mi = 0; mi < 4; ++mi)
      a[mi] = *(const bf16x8*)&As[waveM + mi * 16 + col][quad * 8];
#pragma unroll
    for (int ni = 0; ni < 4; ++ni)
      b[ni] = *(const bf16x8*)&Bs[waveN + ni * 16 + col][quad * 8];
#pragma unroll
    for (int mi = 0; mi < 4; ++mi)
#pragma unroll
      for (int ni = 0; ni < 4; ++ni)
        acc[mi][ni] = __builtin_amdgcn_mfma_f32_16x16x32_bf16(
            a[mi], b[ni], acc[mi][ni], 0, 0, 0);
    __syncthreads();
  }

  // ---- epilogue: C/D layout is D[m = quad*4 + r][n = col] per 16x16 frag ----
  const int i0 = bi * 128 + waveM;
  const int j0 = bj * 128 + waveN;
  int labj[4];
  float sqj[4];
#pragma unroll
  for (int ni = 0; ni < 4; ++ni) {
    int j = j0 + ni * 16 + col;
    labj[ni] = lab[j];
    sqj[ni] = sq[j];
  }
#pragma unroll
  for (int mi = 0; mi < 4; ++mi) {
#pragma unroll
    for (int r = 0; r < 4; ++r) {
      int i = i0 + mi * 16 + quad * 4 + r;
      float sqi = sq[i];
      int li = lab[i];
      float rs = 0.f;
#pragma unroll
      for (int ni = 0; ni < 4; ++ni) {
        int j = j0 + ni * 16 + col;
        float g = acc[mi][ni][r];
        float d2 = fmaxf(sqi + sqj[ni] - 2.f * g, 0.f);
        float dist = sqrtf(d2);
        float c = (li == labj[ni]) ? dist : -dist;
        rs += (i == j) ? 0.f : c;
      }
      // reduce across the 16 lanes sharing this row (same quad)
      rs += __shfl_xor(rs, 1);
      rs += __shfl_xor(rs, 2);
      rs += __shfl_xor(rs, 4);
      rs += __shfl_xor(rs, 8);
      if (col == 0) atomicAdd(&accrow[i], rs);
    }
  }
}

// ---------------- final mean ----------------
__global__ __launch_bounds__(256) void reduce_kernel(
    const float* __restrict__ accrow, float* __restrict__ out) {
  __shared__ double wsum[4];
  double s = 0.0;
  for (int i = threadIdx.x; i < N; i += 256) s += (double)accrow[i];
#pragma unroll
  for (int m = 32; m; m >>= 1) s += __shfl_xor(s, m);
  if ((threadIdx.x & 63) == 0) wsum[threadIdx.x >> 6] = s;
  __syncthreads();
  if (threadIdx.x == 0)
    out[0] = (float)((wsum[0] + wsum[1] + wsum[2] + wsum[3]) / (double)N);
}

extern "C" void kernel_launch(void* const* d_in, const int* in_sizes, int n_in,
                              void* d_out, int out_size, void* d_ws, size_t ws_size,
                              hipStream_t stream) {
  const float* x = (const float*)d_in[0];
  const int* labels = (const int*)d_in[1];
  char* ws = (char*)d_ws;
  __hip_bfloat16* xb = (__hip_bfloat16*)ws;                        // N*KP*2 = 3.67 MB
  float* sq = (float*)(ws + (size_t)N * KP * 2);                   // N*4
  int* lab = (int*)(ws + (size_t)N * KP * 2 + (size_t)N * 4);      // N*4
  float* accrow = (float*)(ws + (size_t)N * KP * 2 + (size_t)N * 8); // N*4
  float* out = (float*)d_out;

  prep_kernel<<<N / 4, 256, 0, stream>>>(x, labels, xb, sq, lab, accrow);
  dim3 grid(N / 128, N / 128);
  gram_kernel<<<grid, 256, 0, stream>>>(xb, sq, lab, accrow);
  reduce_kernel<<<1, 256, 0, stream>>>(accrow, out);
}

// Round 2
// 112.534 us; speedup vs baseline: 1.6755x; 1.6755x over previous
//
#include <hip/hip_runtime.h>
#include <hip/hip_bf16.h>

#define N 8192
#define D 200
#define KP 224      // K padded to 7 * 32
#define NSTEP 7
#define NB 64       // 8192 / 128 block-tiles per dim
#define NTRI (NB * (NB + 1) / 2)   // 2080 triangular blocks
#define NPART (NTRI * 4)           // one partial per wave

typedef __bf16 bf16x8 __attribute__((ext_vector_type(8)));
typedef float f32x4 __attribute__((ext_vector_type(4)));

// ---------------- prep: cast to bf16 (padded), row norms, labels ----
__global__ __launch_bounds__(256) void prep_kernel(
    const float* __restrict__ x, const int* __restrict__ labels,
    __hip_bfloat16* __restrict__ xb, float* __restrict__ sq,
    int* __restrict__ lab) {
  int row = blockIdx.x * 4 + (threadIdx.x >> 6);   // one wave per row
  int lane = threadIdx.x & 63;
  const float* xr = x + (size_t)row * D;
  __hip_bfloat16* xbr = xb + (size_t)row * KP;
  float s = 0.f;
#pragma unroll
  for (int c = 0; c < 4; ++c) {
    int k = lane + c * 64;                          // covers 0..255
    float f = (k < D) ? xr[k] : 0.f;
    __hip_bfloat16 h = __float2bfloat16(f);
    float fb = __bfloat162float(h);
    if (k < KP) xbr[k] = h;
    s += fb * fb;                                   // norm of the bf16-rounded row
  }
#pragma unroll
  for (int m = 32; m; m >>= 1) s += __shfl_xor(s, m);
  if (lane == 0) {
    sq[row] = s;
    lab[row] = labels[row];
  }
}

// ------- triangular 128x128 MFMA tile, no LDS, scalar-sum epilogue -------
__global__ __launch_bounds__(256) void gram_kernel(
    const __hip_bfloat16* __restrict__ xb, const float* __restrict__ sq,
    const int* __restrict__ lab, double* __restrict__ partial) {
  // decode linear block id -> (bi <= bj) upper-triangular pair
  const int p = blockIdx.x;
  int bi = (int)((129.0f - __builtin_sqrtf(129.0f * 129.0f - 8.0f * (float)p)) * 0.5f);
  // fixup against fp rounding; offset(b) = b*NB - b*(b-1)/2
  while ((bi + 1) * NB - ((bi + 1) * bi) / 2 <= p) ++bi;
  while (bi * NB - (bi * (bi - 1)) / 2 > p) --bi;
  const int bj = bi + (p - (bi * NB - (bi * (bi - 1)) / 2));

  const int t = threadIdx.x;
  const int wid = t >> 6, lane = t & 63;
  const int col = lane & 15, quad = lane >> 4;
  const int waveM = (wid >> 1) * 64, waveN = (wid & 1) * 64;
  const int i0 = bi * 128 + waveM;
  const int j0 = bj * 128 + waveN;

  f32x4 acc[4][4] = {};

  // fragment loads straight from global (L2-resident, 16B aligned per lane)
#pragma unroll
  for (int step = 0; step < NSTEP; ++step) {
    bf16x8 a[4], b[4];
#pragma unroll
    for (int mi = 0; mi < 4; ++mi)
      a[mi] = *(const bf16x8*)(xb + (size_t)(i0 + mi * 16 + col) * KP + step * 32 + quad * 8);
#pragma unroll
    for (int ni = 0; ni < 4; ++ni)
      b[ni] = *(const bf16x8*)(xb + (size_t)(j0 + ni * 16 + col) * KP + step * 32 + quad * 8);
#pragma unroll
    for (int mi = 0; mi < 4; ++mi)
#pragma unroll
      for (int ni = 0; ni < 4; ++ni)
        acc[mi][ni] = __builtin_amdgcn_mfma_f32_16x16x32_bf16(
            a[mi], b[ni], acc[mi][ni], 0, 0, 0);
  }

  // ---- epilogue: D[m = quad*4 + r][n = col]; accumulate one scalar ----
  int labj[4];
  float sqj[4];
#pragma unroll
  for (int ni = 0; ni < 4; ++ni) {
    int j = j0 + ni * 16 + col;
    labj[ni] = lab[j];
    sqj[ni] = sq[j];
  }
  float rs = 0.f;
#pragma unroll
  for (int mi = 0; mi < 4; ++mi) {
#pragma unroll
    for (int r = 0; r < 4; ++r) {
      int i = i0 + mi * 16 + quad * 4 + r;
      float sqi = sq[i];
      int li = lab[i];
#pragma unroll
      for (int ni = 0; ni < 4; ++ni) {
        int j = j0 + ni * 16 + col;
        float g = acc[mi][ni][r];
        float d2 = fmaxf(fmaf(-2.f, g, sqi + sqj[ni]), 0.f);
        float dist = __builtin_sqrtf(d2);
        float c = (li == labj[ni]) ? dist : -dist;
        rs += (i == j) ? 0.f : c;
      }
    }
  }
#pragma unroll
  for (int m = 32; m; m >>= 1) rs += __shfl_xor(rs, m);
  if (lane == 0) {
    double w = (bi == bj) ? 1.0 : 2.0;   // mirror tile not launched
    partial[p * 4 + wid] = w * (double)rs;
  }
}

// ---------------- final mean ----------------
__global__ __launch_bounds__(256) void reduce_kernel(
    const double* __restrict__ partial, float* __restrict__ out) {
  __shared__ double wsum[4];
  double s = 0.0;
  for (int i = threadIdx.x; i < NPART; i += 256) s += partial[i];
#pragma unroll
  for (int m = 32; m; m >>= 1) s += __shfl_xor(s, m);
  if ((threadIdx.x & 63) == 0) wsum[threadIdx.x >> 6] = s;
  __syncthreads();
  if (threadIdx.x == 0)
    out[0] = (float)((wsum[0] + wsum[1] + wsum[2] + wsum[3]) / (double)N);
}

extern "C" void kernel_launch(void* const* d_in, const int* in_sizes, int n_in,
                              void* d_out, int out_size, void* d_ws, size_t ws_size,
                              hipStream_t stream) {
  const float* x = (const float*)d_in[0];
  const int* labels = (const int*)d_in[1];
  char* ws = (char*)d_ws;
  __hip_bfloat16* xb = (__hip_bfloat16*)ws;                          // N*KP*2 = 3.67 MB
  float* sq = (float*)(ws + (size_t)N * KP * 2);                     // N*4
  int* lab = (int*)(ws + (size_t)N * KP * 2 + (size_t)N * 4);        // N*4
  double* partial = (double*)(ws + (size_t)N * KP * 2 + (size_t)N * 8);  // NPART*8
  float* out = (float*)d_out;

  prep_kernel<<<N / 4, 256, 0, stream>>>(x, labels, xb, sq, lab);
  gram_kernel<<<NTRI, 256, 0, stream>>>(xb, sq, lab, partial);
  reduce_kernel<<<1, 256, 0, stream>>>(partial, out);
}